// Round 7
// baseline (121.782 us; speedup 1.0000x reference)
//
#include <hip/hip_runtime.h>

#define N_ATOMS 10000
#define N_EDGES 200000
#define GA 2           // atoms per block (2 consumer waves)
#define EB 112         // LDS rows per batch; 112*44*4 = 19712 B -> 8 blocks/CU
#define ROW 44         // dwords per feature row
#define W_F 0.6283185307179586f   // pi/5 in f32

// 64-ary lane-parallel lower_bound over closed candidate range [lo, hi].
__device__ __forceinline__ int lb64(const int* __restrict__ a, int lo, int hi, int v, int lane) {
    while (lo < hi) {
        const int len  = hi - lo;
        const int step = (len + 63) >> 6;
        const int p    = lo + lane * step;
        const unsigned long long m = __ballot((p < hi) && (a[p] < v));
        const int nb = __popcll(m);
        if (nb == 0) { hi = lo; break; }
        const int lastlt = lo + (nb - 1) * step;   // a[lastlt] < v
        lo = lastlt + 1;
        hi = min(lastlt + step, hi);
    }
    return lo;
}

// lower_bound(seg_i, v) with statistical window (sd of starts[v]-20v <= 224; +-2048 = 9 sigma)
__device__ __forceinline__ int seg_lb(const int* __restrict__ a, int v, int lane) {
    int lo = 0, hi = N_EDGES;
    const int est = 20 * v;
    int wlo = est - 2048; if (wlo < 0) wlo = 0;
    int whi = est + 2048; if (whi > N_EDGES) whi = N_EDGES;
    const bool ok = ((wlo == 0) || (a[wlo - 1] < v)) && ((whi == N_EDGES) || (a[whi] >= v));
    if (ok) { lo = wlo; hi = whi; }   // else provably-correct full-range fallback
    return lb64(a, lo, hi, v, lane);
}

// waves 0-1: producers (stage features to LDS). waves 2-3: consumers (one atom each).
// __launch_bounds__(256,8): force <=64 VGPR so 8 waves/SIMD (occupancy cliff at 64 - m69).
__global__ __launch_bounds__(256, 8) void sph_kernel(
    const float* __restrict__ R,
    const int*   __restrict__ seg_i,
    const int*   __restrict__ idx_j,
    const int*   __restrict__ species,
    const float* __restrict__ emb,
    float*       __restrict__ out)
{
    __shared__ float feat[EB][ROW];
    const int tid  = threadIdx.x;
    const int wave = tid >> 6;
    const int lane = tid & 63;
    const int gb   = blockIdx.x * GA;

    // every wave computes all three segment boundaries (uniform loop bounds)
    const int s0 = seg_lb(seg_i, gb,     lane);
    const int s1 = seg_lb(seg_i, gb + 1, lane);
    const int s2 = seg_lb(seg_i, gb + 2, lane);

    // ---- consumer tile decode: 43 active lanes, each 2m x 4n x 4c = 32 outputs ----
    int n0 = 0, m0 = 0, m1 = 0, nl = 0, pidx = 0, stride = 0; long base = 0;
    if (lane < 5)        { n0 = 4*lane;                                   m0 = 0; m1 = 0;                        nl = 20; pidx = 0;       base = 0;       stride = 80;  }
    else if (lane < 15)  { int q = lane-5;  int pr = q/5;  n0 = 4*(q%5);  m0 = 2*pr; m1 = (m0+1 < 3) ? m0+1 : 2; nl = 18; pidx = 1 + pr;  base = 800000;  stride = 216; }
    else if (lane < 27)  { int q = lane-15; int pr = q/4;  n0 = 4*(q%4);  m0 = 2*pr; m1 = (m0+1 < 5) ? m0+1 : 4; nl = 16; pidx = 3 + pr;  base = 2960000; stride = 320; }
    else if (lane < 43)  { int q = lane-27; int pr = q/4;  n0 = 4*(q%4);  m0 = 2*pr; m1 = (m0+1 < 7) ? m0+1 : 6; nl = 14; pidx = 6 + pr;  base = 6160000; stride = 392; }
    const bool consumer = (wave >= 2);
    const bool racc     = consumer && (lane < 43);
    const int  atom     = gb + (wave - 2);
    const int  astart   = (wave == 2) ? s0 : s1;
    const int  aend     = (wave == 2) ? s1 : s2;

    float4 acc[8];
    #pragma unroll
    for (int k = 0; k < 8; ++k) acc[k] = float4{0.f, 0.f, 0.f, 0.f};

    for (int e0 = s0; e0 < s2; e0 += EB) {
        const int cnt = min(EB, s2 - e0);
        __syncthreads();   // previous batch fully consumed
        if (tid < 128) {
            // ---- producers: stage edges e0+t, t = tid, tid+128... (cnt <= 112 so one pass) ----
            for (int t = tid; t < cnt; t += 128) {
                const int g = e0 + t;
                const int jj = idx_j[g];
                const float x = R[3*g + 0];
                const float y = R[3*g + 1];
                const float z = R[3*g + 2];
                const int sidx = species[jj];
                const float r   = sqrtf(x*x + y*y + z*z);
                const float inv = 1.0f / (r + 1e-12f);
                const float ux = x*inv, uy = y*inv, uz = z*inv;
                const float4 spv = *(const float4*)&emb[4 * sidx];

                const float t1 = W_F * r;
                const float s1f = sinf(t1);
                const float c1f = cosf(t1);
                const float fc  = (r < 5.0f) ? (0.5f * (c1f + 1.0f)) : 0.0f;
                const float c2x = 2.0f * c1f;

                float4* row = (float4*)&feat[t][0];
                // radial: Chebyshev recurrence, packed+stored in quads (low liveness)
                {
                    float sk_2 = 0.0f, sk_1 = s1f;
                    #pragma unroll
                    for (int qd = 0; qd < 5; ++qd) {
                        float q0, q1, q2, q3;
                        if (qd == 0) { q0 = s1f; }
                        else { const float sk = c2x*sk_1 - sk_2; sk_2 = sk_1; sk_1 = sk; q0 = sk; }
                        { const float sk = c2x*sk_1 - sk_2; sk_2 = sk_1; sk_1 = sk; q1 = sk; }
                        { const float sk = c2x*sk_1 - sk_2; sk_2 = sk_1; sk_1 = sk; q2 = sk; }
                        { const float sk = c2x*sk_1 - sk_2; sk_2 = sk_1; sk_1 = sk; q3 = sk; }
                        row[qd] = float4{q0*fc, q1*fc, q2*fc, q3*fc};
                    }
                }
                const float x2 = ux*ux, y2 = uy*uy, z2 = uz*uz;
                const float c1a = 0.4886025119029199f;
                const float c2a = 1.0925484305920792f;
                // angular pairs (pidx): 0:(a0,a0) 1:(a1,a2) 2:(a3,a3) 3:(a4,a5) 4:(a6,a7)
                //                       5:(a8,a8) 6:(a9,a10) 7:(a11,a12) 8:(a13,a14) 9:(a15,a15)
                row[5] = float4{0.28209479177387814f, 0.28209479177387814f, c1a*uy, c1a*uz};
                row[6] = float4{c1a*ux, c1a*ux, c2a*ux*uy, c2a*uy*uz};
                row[7] = float4{0.31539156525252005f*(3.0f*z2-1.0f), c2a*ux*uz,
                                0.5462742152960396f*(x2-y2), 0.5462742152960396f*(x2-y2)};
                row[8] = float4{0.5900435899266435f*uy*(3.0f*x2-y2), 2.890611442640554f*ux*uy*uz,
                                0.4570457994644658f*uy*(5.0f*z2-1.0f), 0.3731763325901154f*uz*(5.0f*z2-3.0f)};
                row[9] = float4{0.4570457994644658f*ux*(5.0f*z2-1.0f), 1.445305721320277f*uz*(x2-y2),
                                0.5900435899266435f*ux*(x2-3.0f*y2), 0.5900435899266435f*ux*(x2-3.0f*y2)};
                row[10] = spv;
            }
        }
        __syncthreads();   // staging visible to consumers
        if (racc) {
            const int lo = max(astart, e0);
            const int hi = min(aend, e0 + cnt);
            const float* f = &feat[lo - e0][0];
            for (int t = lo; t < hi; ++t, f += ROW) {
                const float4 rq = *(const float4*)(f + n0);
                const float2 ap = *(const float2*)(f + 20 + 2*pidx);
                const float4 sv = *(const float4*)(f + 40);
                const float rr[4] = {rq.x, rq.y, rq.z, rq.w};
                const float aa[2] = {ap.x, ap.y};
                #pragma unroll
                for (int mi = 0; mi < 2; ++mi) {
                    #pragma unroll
                    for (int ni = 0; ni < 4; ++ni) {
                        const float p = rr[ni] * aa[mi];
                        float4& A = acc[mi*4 + ni];
                        A.x += p * sv.x; A.y += p * sv.y; A.z += p * sv.z; A.w += p * sv.w;
                    }
                }
            }
        }
    }

    if (racc) {   // every atom's 1008 outputs written (zeros if no edges)
        float* ob = out + base + (size_t)atom * (size_t)stride;
        #pragma unroll
        for (int mi = 0; mi < 2; ++mi) {
            if (mi == 0 || m1 != m0) {
                const int m = mi ? m1 : m0;
                #pragma unroll
                for (int ni = 0; ni < 4; ++ni) {
                    const int n = n0 + ni;
                    if (n < nl) *(float4*)(ob + (size_t)(m*nl + n)*4) = acc[mi*4 + ni];
                }
            }
        }
    }
}

extern "C" void kernel_launch(void* const* d_in, const int* in_sizes, int n_in,
                              void* d_out, int out_size, void* d_ws, size_t ws_size,
                              hipStream_t stream) {
    const float* R    = (const float*)d_in[0];
    const int*   i_   = (const int*)  d_in[1];
    const int*   j_   = (const int*)  d_in[2];
    const int*   sp   = (const int*)  d_in[3];
    const float* emb  = (const float*)d_in[4];
    float* out = (float*)d_out;

    sph_kernel<<<N_ATOMS / GA, 256, 0, stream>>>(R, i_, j_, sp, emb, out);
}